// Round 8
// baseline (731.960 us; speedup 1.0000x reference)
//
#include <hip/hip_runtime.h>
#include <math.h>

typedef __attribute__((ext_vector_type(8))) short short8;
typedef __attribute__((ext_vector_type(4))) float f32x4;
typedef __attribute__((address_space(3))) void lds_void;
typedef const __attribute__((address_space(1))) void glb_void;

#define N_NODES 50000
#define NUM_REL 8
#define IN_DIM 128
#define HID 256
#define E_EDGES 1600000
#define M_DEC 200000
#define K1 1152
#define K2 2304
#define LN_EPS 1e-5f
#define NSEG (N_NODES * 8)            /* per-(node,rel) segments */
#define NB2 782                       /* coarse buckets = ceil(N/64) */
#define SA_WG 391                     /* ceil(E/4096) */
#define SA_CH 4096
#define SA_DCH 512

__device__ __forceinline__ float b2f(ushort u) {
    union { unsigned int i; float f; } v; v.i = ((unsigned int)u) << 16; return v.f;
}
__device__ __forceinline__ ushort f2b(float f) {
    union { float f; unsigned int i; } v; v.f = f;
    unsigned int r = v.i + 0x7FFFu + ((v.i >> 16) & 1u);
    return (ushort)(r >> 16);
}
__device__ __forceinline__ unsigned int pk2(ushort a, ushort b) {
    return (unsigned int)a | ((unsigned int)b << 16);
}
// fast gelu (tanh form, native exp/rcp): |err| <= ~3e-3 absolute, fine at 2% rel tol
__device__ __forceinline__ float gelu_fast(float x) {
    float y = 1.5957691216f * (x + 0.044715f * x * x * x);   // 2*sqrt(2/pi)*(...)
    float e = __expf(y);
    float t = 1.f - 2.f * __builtin_amdgcn_rcpf(e + 1.f);
    return 0.5f * x * (1.f + t);
}
__device__ __forceinline__ int clampn(int v) {
    if ((unsigned)v >= N_NODES) v = (v < 0) ? 0 : N_NODES - 1;
    return v;
}

// ================= two-level bucket sort (no per-edge global atomics) =================

__global__ __launch_bounds__(256) void coarse_count(const int* __restrict__ ei,
                                                    const int* __restrict__ dec,
                                                    int* __restrict__ bh, int* __restrict__ dh) {
    __shared__ int lb[NB2], ld[NB2];
    const int t = threadIdx.x;
    for (int i = t; i < NB2; i += 256) { lb[i] = 0; ld[i] = 0; }
    __syncthreads();
    const int e0 = blockIdx.x * SA_CH;
#pragma unroll
    for (int k = 0; k < 16; ++k) {
        int e = e0 + k * 256 + t;
        if (e < E_EDGES) {
            int dst = clampn(ei[E_EDGES + e]);
            atomicAdd(&lb[dst >> 6], 1);
        }
    }
    const int d0 = blockIdx.x * SA_DCH;
#pragma unroll
    for (int k = 0; k < 2; ++k) {
        int i = d0 + k * 256 + t;
        if (i < M_DEC) {
            int a = clampn(dec[(size_t)i * 2]);
            atomicAdd(&ld[a >> 6], 1);
        }
    }
    __syncthreads();
    for (int i = t; i < NB2; i += 256) {
        if (lb[i]) atomicAdd(&bh[i], lb[i]);
        if (ld[i]) atomicAdd(&dh[i], ld[i]);
    }
}

__global__ __launch_bounds__(1024) void scan_buckets(const int* __restrict__ bh, int* __restrict__ bbase,
                                                     int* __restrict__ bcur,
                                                     const int* __restrict__ dh, int* __restrict__ dbase,
                                                     int* __restrict__ dcur, int* __restrict__ rp2) {
    __shared__ int ts[1024];
    const int t = threadIdx.x;
    const int* src = (blockIdx.x == 0) ? bh : dh;
    int* ob = (blockIdx.x == 0) ? bbase : dbase;
    int* oc = (blockIdx.x == 0) ? bcur : dcur;
    int v = (t < NB2) ? src[t] : 0;
    ts[t] = v;
    __syncthreads();
#pragma unroll
    for (int off = 1; off < 1024; off <<= 1) {
        int u = (t >= off) ? ts[t - off] : 0;
        __syncthreads();
        ts[t] += u;
        __syncthreads();
    }
    if (t < NB2) { int ex = ts[t] - v; ob[t] = ex; oc[t] = ex; }
    if (t == NB2 - 1) ob[NB2] = ts[t];
    if (t == 0 && blockIdx.x == 0) rp2[NSEG] = E_EDGES;
}

__global__ __launch_bounds__(256) void stageA(const int* __restrict__ ei, const int* __restrict__ et,
                                              int* __restrict__ bcur, unsigned int* __restrict__ sbuf,
                                              const int* __restrict__ dec, int* __restrict__ dcur,
                                              int* __restrict__ perm) {
    __shared__ int h[NB2], base_[NB2];
    const int t = threadIdx.x;
    const int e0 = blockIdx.x * SA_CH;
    for (int i = t; i < NB2; i += 256) h[i] = 0;
    __syncthreads();
    int myb[16];
#pragma unroll
    for (int k = 0; k < 16; ++k) {
        int e = e0 + k * 256 + t;
        int b = -1;
        if (e < E_EDGES) {
            int dst = clampn(ei[E_EDGES + e]);
            b = dst >> 6;
            atomicAdd(&h[b], 1);
        }
        myb[k] = b;
    }
    __syncthreads();
    for (int i = t; i < NB2; i += 256) {
        int c = h[i];
        base_[i] = c ? atomicAdd(&bcur[i], c) : 0;
    }
    __syncthreads();
    for (int i = t; i < NB2; i += 256) h[i] = 0;
    __syncthreads();
#pragma unroll
    for (int k = 0; k < 16; ++k) {
        int e = e0 + k * 256 + t;
        int b = myb[k];
        if (b >= 0) {
            int dst = clampn(ei[E_EDGES + e]);
            int src = clampn(ei[e]);
            int r = et[e] & 7;
            int off = atomicAdd(&h[b], 1);
            sbuf[base_[b] + off] =
                (unsigned)src | ((unsigned)r << 16) | ((unsigned)(dst & 63) << 19);
        }
    }
    // ---- decode perm bucketing ----
    __syncthreads();
    for (int i = t; i < NB2; i += 256) h[i] = 0;
    __syncthreads();
    const int d0 = blockIdx.x * SA_DCH;
    int dbk[2];
#pragma unroll
    for (int k = 0; k < 2; ++k) {
        int i = d0 + k * 256 + t;
        int b = -1;
        if (i < M_DEC) {
            int a = clampn(dec[(size_t)i * 2]);
            b = a >> 6;
            atomicAdd(&h[b], 1);
        }
        dbk[k] = b;
    }
    __syncthreads();
    for (int i = t; i < NB2; i += 256) {
        int c = h[i];
        base_[i] = c ? atomicAdd(&dcur[i], c) : 0;
    }
    __syncthreads();
    for (int i = t; i < NB2; i += 256) h[i] = 0;
    __syncthreads();
#pragma unroll
    for (int k = 0; k < 2; ++k) {
        int i = d0 + k * 256 + t;
        int b = dbk[k];
        if (b >= 0) {
            int off = atomicAdd(&h[b], 1);
            perm[base_[b] + off] = i;
        }
    }
}

__global__ __launch_bounds__(512) void stageB(const unsigned int* __restrict__ sbuf,
                                              const int* __restrict__ bbase,
                                              int* __restrict__ rp2,
                                              unsigned int* __restrict__ epk) {
    __shared__ int cnt[512];
    __shared__ int pref[512];
    const int t = threadIdx.x;
    const int b = blockIdx.x;
    const int s0 = bbase[b], s1 = bbase[b + 1];
    cnt[t] = 0;
    __syncthreads();
    for (int i = s0 + t; i < s1; i += 512) {
        unsigned int p = sbuf[i];
        int ls = (((p >> 19) & 63) << 3) | ((p >> 16) & 7);
        atomicAdd(&cnt[ls], 1);
    }
    __syncthreads();
    pref[t] = cnt[t];
    __syncthreads();
#pragma unroll
    for (int off = 1; off < 512; off <<= 1) {
        int u = (t >= off) ? pref[t - off] : 0;
        __syncthreads();
        pref[t] += u;
        __syncthreads();
    }
    int excl = pref[t] - cnt[t];
    int seg = b * 512 + t;
    if (seg < NSEG) rp2[seg] = s0 + excl;
    __syncthreads();
    pref[t] = excl;
    cnt[t] = 0;
    __syncthreads();
    for (int i = s0 + t; i < s1; i += 512) {
        unsigned int p = sbuf[i];
        int ls = (((p >> 19) & 63) << 3) | ((p >> 16) & 7);
        int off = atomicAdd(&cnt[ls], 1);
        epk[s0 + pref[ls] + off] = p & 0xFFFFu;
    }
}

// ---------------- merged pack: xconv + enc weights + mlp weights ----------------
__global__ void pack_all(const float* __restrict__ x, ushort* __restrict__ xb,
                         const float* __restrict__ root1, const float* __restrict__ W1,
                         const float* __restrict__ root2, const float* __restrict__ W2,
                         ushort* __restrict__ B1t, ushort* __restrict__ B2t,
                         const float* __restrict__ mw1, const float* __restrict__ mw2,
                         ushort* __restrict__ wuvt, ushort* __restrict__ w2t) {
    const int XC = N_NODES * IN_DIM / 4;
    const int N1 = HID * K1;
    const int N2 = HID * K2;
    const int NU = 512 * 256;
    const int NW = 128 * 256;
    int idx = blockIdx.x * 256 + threadIdx.x;
    if (idx < XC) {
        float4 v = *(const float4*)(x + (size_t)idx * 4);
        uint2 o;
        o.x = pk2(f2b(v.x), f2b(v.y));
        o.y = pk2(f2b(v.z), f2b(v.w));
        *(uint2*)(xb + (size_t)idx * 4) = o;
        return;
    }
    idx -= XC;
    if (idx < N1) {
        int n = idx / K1, k = idx % K1;
        float v;
        if (k < IN_DIM) v = root1[k * HID + n];
        else { int kk = k - IN_DIM; v = W1[(size_t)(kk >> 7) * IN_DIM * HID + (kk & 127) * HID + n]; }
        B1t[(size_t)n * K1 + k] = f2b(v);
        return;
    }
    idx -= N1;
    if (idx < N2) {
        int n = idx / K2, k = idx % K2;
        float v;
        if (k < HID) v = root2[k * HID + n];
        else { int kk = k - HID; v = W2[(size_t)(kk >> 8) * HID * HID + (kk & 255) * HID + n]; }
        B2t[(size_t)n * K2 + k] = f2b(v);
        return;
    }
    idx -= N2;
    if (idx < NU) {
        int n = idx / 256, k = idx % 256;
        float v = (n < 256) ? mw1[(size_t)k * 256 + n] : mw1[(size_t)(256 + k) * 256 + (n - 256)];
        wuvt[(size_t)n * 256 + k] = f2b(v);
        return;
    }
    idx -= NU;
    if (idx < NW) {
        int n = idx / 256, k = idx % 256;
        w2t[n * 256 + k] = f2b(mw2[k * 128 + n]);
    }
}

// ---------------- aggregation: wave-per-node over rel-sorted segments (round-4 form) ----

#define FL1() { int c_ = segend - segbeg; float inv_ = c_ > 0 ? 1.f / (float)c_ : 0.f; \
    *(unsigned int*)(Arow + IN_DIM + r * IN_DIM + 2 * lane) = \
        pk2(f2b((aA.x + aB.x) * inv_), f2b((aA.y + aB.y) * inv_)); \
    aA.x = 0.f; aA.y = 0.f; aB.x = 0.f; aB.y = 0.f; \
    ++r; segbeg = segend; segend = (r < 8) ? rp[r + 1] : end; \
    if (segend < segbeg) segend = segbeg; if (segend > end) segend = end; }
#define CK1(EI) { while (r < 8 && (EI) >= segend) FL1(); }
#define AC1A(U) { aA.x += b2f((ushort)((U) & 0xFFFFu)); aA.y += b2f((ushort)((U) >> 16)); }
#define AC1B(U) { aB.x += b2f((ushort)((U) & 0xFFFFu)); aB.y += b2f((ushort)((U) >> 16)); }

__global__ __launch_bounds__(256) void agg1_kernel(const ushort* __restrict__ xb,
                                                   const int* __restrict__ rp2,
                                                   const unsigned int* __restrict__ epk,
                                                   ushort* __restrict__ Achunk, int n0, int m) {
    const int w = threadIdx.x >> 6, lane = threadIdx.x & 63;
    const int local = blockIdx.x * 4 + w;
    if (local >= m) return;
    const int n = n0 + local;
    const int* rp = rp2 + n * 8;
    ushort* Arow = Achunk + (size_t)local * K1;
    const ushort* xbb = xb + 2 * lane;
    *(unsigned int*)(Arow + 2 * lane) = *(const unsigned int*)(xb + (size_t)n * IN_DIM + 2 * lane);

    int beg = rp[0], end = rp[8];
    if (beg < 0) beg = 0;
    if (end > E_EDGES) end = E_EDGES;
    if (end < beg) end = beg;

    float2 aA = {0.f, 0.f}, aB = {0.f, 0.f};
    int r = 0, segbeg = beg, segend = rp[1];
    if (segend < segbeg) segend = segbeg; if (segend > end) segend = end;

    int e = beg;
    for (; e + 7 < end; e += 8) {
        unsigned int p0 = epk[e],     p1 = epk[e + 1], p2 = epk[e + 2], p3 = epk[e + 3];
        unsigned int p4 = epk[e + 4], p5 = epk[e + 5], p6 = epk[e + 6], p7 = epk[e + 7];
        unsigned int u0 = *(const unsigned int*)(xbb + (size_t)p0 * IN_DIM);
        unsigned int u1 = *(const unsigned int*)(xbb + (size_t)p1 * IN_DIM);
        unsigned int u2 = *(const unsigned int*)(xbb + (size_t)p2 * IN_DIM);
        unsigned int u3 = *(const unsigned int*)(xbb + (size_t)p3 * IN_DIM);
        unsigned int u4 = *(const unsigned int*)(xbb + (size_t)p4 * IN_DIM);
        unsigned int u5 = *(const unsigned int*)(xbb + (size_t)p5 * IN_DIM);
        unsigned int u6 = *(const unsigned int*)(xbb + (size_t)p6 * IN_DIM);
        unsigned int u7 = *(const unsigned int*)(xbb + (size_t)p7 * IN_DIM);
        CK1(e)     AC1A(u0) CK1(e + 1) AC1B(u1)
        CK1(e + 2) AC1A(u2) CK1(e + 3) AC1B(u3)
        CK1(e + 4) AC1A(u4) CK1(e + 5) AC1B(u5)
        CK1(e + 6) AC1A(u6) CK1(e + 7) AC1B(u7)
    }
    for (; e < end; ++e) {
        unsigned int p = epk[e];
        unsigned int u = *(const unsigned int*)(xbb + (size_t)p * IN_DIM);
        CK1(e) AC1A(u)
    }
    while (r < 8) FL1();
}

#define FL2() { int c_ = segend - segbeg; float inv_ = c_ > 0 ? 1.f / (float)c_ : 0.f; \
    f32x4 t_ = aA + aB; uint2 o_; \
    o_.x = pk2(f2b(t_[0] * inv_), f2b(t_[1] * inv_)); \
    o_.y = pk2(f2b(t_[2] * inv_), f2b(t_[3] * inv_)); \
    *(uint2*)(Arow + HID + r * HID + 4 * lane) = o_; \
    aA = (f32x4){0.f, 0.f, 0.f, 0.f}; aB = aA; \
    ++r; segbeg = segend; segend = (r < 8) ? rp[r + 1] : end; \
    if (segend < segbeg) segend = segbeg; if (segend > end) segend = end; }
#define CK2(EI) { while (r < 8 && (EI) >= segend) FL2(); }
#define AC2A(U) { f32x4 f_; \
    f_[0] = b2f((ushort)((U).x & 0xFFFFu)); f_[1] = b2f((ushort)((U).x >> 16)); \
    f_[2] = b2f((ushort)((U).y & 0xFFFFu)); f_[3] = b2f((ushort)((U).y >> 16)); aA += f_; }
#define AC2B(U) { f32x4 f_; \
    f_[0] = b2f((ushort)((U).x & 0xFFFFu)); f_[1] = b2f((ushort)((U).x >> 16)); \
    f_[2] = b2f((ushort)((U).y & 0xFFFFu)); f_[3] = b2f((ushort)((U).y >> 16)); aB += f_; }

__global__ __launch_bounds__(256) void agg2_kernel(const ushort* __restrict__ h1,
                                                   const int* __restrict__ rp2,
                                                   const unsigned int* __restrict__ epk,
                                                   ushort* __restrict__ Achunk, int n0, int m) {
    const int w = threadIdx.x >> 6, lane = threadIdx.x & 63;
    const int local = blockIdx.x * 4 + w;
    if (local >= m) return;
    const int n = n0 + local;
    const int* rp = rp2 + n * 8;
    ushort* Arow = Achunk + (size_t)local * K2;
    const ushort* hb = h1 + 4 * lane;
    *(uint2*)(Arow + 4 * lane) = *(const uint2*)(h1 + (size_t)n * HID + 4 * lane);

    int beg = rp[0], end = rp[8];
    if (beg < 0) beg = 0;
    if (end > E_EDGES) end = E_EDGES;
    if (end < beg) end = beg;

    f32x4 aA = {0.f, 0.f, 0.f, 0.f}, aB = {0.f, 0.f, 0.f, 0.f};
    int r = 0, segbeg = beg, segend = rp[1];
    if (segend < segbeg) segend = segbeg; if (segend > end) segend = end;

    int e = beg;
    for (; e + 7 < end; e += 8) {
        unsigned int p0 = epk[e],     p1 = epk[e + 1], p2 = epk[e + 2], p3 = epk[e + 3];
        unsigned int p4 = epk[e + 4], p5 = epk[e + 5], p6 = epk[e + 6], p7 = epk[e + 7];
        uint2 u0 = *(const uint2*)(hb + (size_t)p0 * HID);
        uint2 u1 = *(const uint2*)(hb + (size_t)p1 * HID);
        uint2 u2 = *(const uint2*)(hb + (size_t)p2 * HID);
        uint2 u3 = *(const uint2*)(hb + (size_t)p3 * HID);
        uint2 u4 = *(const uint2*)(hb + (size_t)p4 * HID);
        uint2 u5 = *(const uint2*)(hb + (size_t)p5 * HID);
        uint2 u6 = *(const uint2*)(hb + (size_t)p6 * HID);
        uint2 u7 = *(const uint2*)(hb + (size_t)p7 * HID);
        CK2(e)     AC2A(u0) CK2(e + 1) AC2B(u1)
        CK2(e + 2) AC2A(u2) CK2(e + 3) AC2B(u3)
        CK2(e + 4) AC2A(u4) CK2(e + 5) AC2B(u5)
        CK2(e + 6) AC2A(u6) CK2(e + 7) AC2B(u7)
    }
    for (; e < end; ++e) {
        unsigned int p = epk[e];
        uint2 u = *(const uint2*)(hb + (size_t)p * HID);
        CK2(e) AC2A(u)
    }
    while (r < 8) FL2();
}

// ---------------- GEMM 128x256 tile, 1024 thr, double-buffered 96KB LDS, vmcnt(3) ------
// B-ingest per output row halved again vs 64-tile (conv2: 910 -> 545 MB staged).
// Wave residency unchanged: was 2 blk/CU x 8 waves, now 1 blk/CU x 16 waves.
// 16 waves = 4 m-quarters x 4 n-strips; per-wave fragment math identical to 64-tile.
// Staging per wave per 64-k step: 1 A-load + 2 B-loads -> vmcnt(3).

#define STAGE(BUF, KO) { \
    __builtin_amdgcn_global_load_lds((glb_void*)(Ab + (KO)), \
        (lds_void*)(AsBase + (BUF) * 8192 + wave * 8 * 64), 16, 0, 0); \
    _Pragma("unroll") \
    for (int j_ = 0; j_ < 2; ++j_) \
        __builtin_amdgcn_global_load_lds((glb_void*)(Bb + (size_t)j_ * 8 * K + (KO)), \
            (lds_void*)(BsBase + (BUF) * 16384 + (wave * 16 + j_ * 8) * 64), 16, 0, 0); }

#define COMPUTE(CUR) { \
    _Pragma("unroll") \
    for (int kk = 0; kk < 2; ++kk) { \
        const int gsw = (((kk * 4 + qd) ^ (cc & 7)) * 8); \
        short8 af[2], bfv[4]; \
        _Pragma("unroll") \
        for (int i = 0; i < 2; ++i) \
            af[i] = *(const short8*)&AsBase[(CUR) * 8192 + (mh * 32 + i * 16 + cc) * 64 + gsw]; \
        _Pragma("unroll") \
        for (int j = 0; j < 4; ++j) \
            bfv[j] = *(const short8*)&BsBase[(CUR) * 16384 + (wn + j * 16 + cc) * 64 + gsw]; \
        _Pragma("unroll") \
        for (int i = 0; i < 2; ++i) \
            _Pragma("unroll") \
            for (int j = 0; j < 4; ++j) \
                acc[i][j] = __builtin_amdgcn_mfma_f32_16x16x32_bf16(af[i], bfv[j], acc[i][j], 0, 0, 0); \
    } }

__global__ __launch_bounds__(1024, 1) void gemm_fused(
    const ushort* __restrict__ A, const ushort* __restrict__ Bt,
    int lda, int M, int K,
    const float* __restrict__ bias, const float* __restrict__ g,
    const float* __restrict__ bvec, const ushort* __restrict__ resid,
    ushort* __restrict__ outp, int ldc, int rowOff) {
    __shared__ __align__(16) ushort smem[49152];  // 96 KB: As[2][128*64] | Bs[2][256*64]
    ushort* AsBase = smem;
    ushort* BsBase = smem + 2 * 128 * 64;
    const int tid = threadIdx.x;
    const int wave = tid >> 6, lane = tid & 63;
    const int w4 = wave & 3, mh = wave >> 2;       // mh in 0..3 (m-quarter)
    const int cc = lane & 15, qd = lane >> 4;
    const int row0 = blockIdx.x * 128;
    const int colBase = blockIdx.y * 256;
    const int wn = w4 * 64;
    const int srow = lane >> 3;
    const int sgrp = (lane & 7) ^ (srow & 7);
    f32x4 acc[2][4];
#pragma unroll
    for (int i = 0; i < 2; ++i)
#pragma unroll
        for (int j = 0; j < 4; ++j) acc[i][j] = (f32x4){0.f, 0.f, 0.f, 0.f};

    // A: 128 rows, wave stages 8 rows (1 instr); B: 256 rows, wave stages 16 rows (2 instr)
    const ushort* Ab = A + (size_t)(row0 + wave * 8 + srow) * lda + sgrp * 8;
    const ushort* Bb = Bt + (size_t)(colBase + wave * 16 + srow) * K + sgrp * 8;

    STAGE(0, 0)
    for (int k0 = 0; k0 < K; k0 += 128) {
        if (k0 + 64 < K) {
            STAGE(1, k0 + 64)
            asm volatile("s_waitcnt vmcnt(3)" ::: "memory");
        } else {
            asm volatile("s_waitcnt vmcnt(0)" ::: "memory");
        }
        __builtin_amdgcn_s_barrier();
        COMPUTE(0)
        asm volatile("s_waitcnt lgkmcnt(0)" ::: "memory");
        __builtin_amdgcn_s_barrier();

        if (k0 + 128 < K) {
            STAGE(0, k0 + 128)
            asm volatile("s_waitcnt vmcnt(3)" ::: "memory");
        } else {
            asm volatile("s_waitcnt vmcnt(0)" ::: "memory");
        }
        __builtin_amdgcn_s_barrier();
        COMPUTE(1)
        asm volatile("s_waitcnt lgkmcnt(0)" ::: "memory");
        __builtin_amdgcn_s_barrier();
    }

    if (g) {
        float* partS = (float*)smem;          // [128][4] aliases dead staging LDS
        float* partQ = (float*)smem + 512;    // [128][4]
        float* muS   = (float*)smem + 1024;   // [128]
        float* rsS   = (float*)smem + 1152;   // [128]
#pragma unroll
        for (int j = 0; j < 4; ++j) {
            float bcol = bias[wn + j * 16 + cc];
#pragma unroll
            for (int i = 0; i < 2; ++i)
#pragma unroll
                for (int r = 0; r < 4; ++r)
                    acc[i][j][r] = fmaxf(acc[i][j][r] + bcol, 0.f);
        }
#pragma unroll
        for (int i = 0; i < 2; ++i)
#pragma unroll
            for (int r = 0; r < 4; ++r) {
                float s = acc[i][0][r] + acc[i][1][r] + acc[i][2][r] + acc[i][3][r];
                float q = acc[i][0][r] * acc[i][0][r] + acc[i][1][r] * acc[i][1][r]
                        + acc[i][2][r] * acc[i][2][r] + acc[i][3][r] * acc[i][3][r];
#pragma unroll
                for (int off = 1; off <= 8; off <<= 1) {
                    s += __shfl_xor(s, off, 64);
                    q += __shfl_xor(q, off, 64);
                }
                if (cc == 0) {
                    int row = mh * 32 + i * 16 + qd * 4 + r;
                    partS[row * 4 + w4] = s;
                    partQ[row * 4 + w4] = q;
                }
            }
        __syncthreads();
        if (tid < 128) {
            float S = partS[tid * 4] + partS[tid * 4 + 1] + partS[tid * 4 + 2] + partS[tid * 4 + 3];
            float Q = partQ[tid * 4] + partQ[tid * 4 + 1] + partQ[tid * 4 + 2] + partQ[tid * 4 + 3];
            float mu = S * (1.f / 256.f);
            float var = Q * (1.f / 256.f) - mu * mu;
            muS[tid] = mu;
            rsS[tid] = rsqrtf(fmaxf(var, 0.f) + LN_EPS);
        }
        __syncthreads();
#pragma unroll
        for (int i = 0; i < 2; ++i)
#pragma unroll
            for (int r = 0; r < 4; ++r) {
                int row = mh * 32 + i * 16 + qd * 4 + r;
                int grow = row0 + row;
                if (grow >= M) continue;
                float mu = muS[row], rs = rsS[row];
                size_t base = (size_t)(rowOff + grow) * ldc;
#pragma unroll
                for (int j = 0; j < 4; ++j) {
                    int col = wn + j * 16 + cc;
                    float val = (acc[i][j][r] - mu) * rs * g[col] + bvec[col];
                    if (resid) val += b2f(resid[base + col]);
                    outp[base + col] = f2b(val);
                }
            }
    } else {
#pragma unroll
        for (int i = 0; i < 2; ++i)
#pragma unroll
            for (int r = 0; r < 4; ++r) {
                int grow = row0 + mh * 32 + i * 16 + qd * 4 + r;
                if (grow >= M) continue;
                size_t base = (size_t)(rowOff + grow) * ldc;
#pragma unroll
                for (int j = 0; j < 4; ++j) {
                    int col = colBase + wn + j * 16 + cc;
                    outp[base + col] = f2b(acc[i][j][r]);
                }
            }
    }
}

// ---------------- edge decode: parallel vectorized stage3 (bank-conflict fix) ------------
__global__ __launch_bounds__(256) void edge_kernel(
    const ushort* __restrict__ uv, const int* __restrict__ dec, const int* __restrict__ perm,
    const float* __restrict__ b1, const ushort* __restrict__ w2t,
    const float* __restrict__ b2, const float* __restrict__ w3,
    const float* __restrict__ b3, float* __restrict__ outp, int M) {
    __shared__ __align__(16) ushort z1s[64][264];
    __shared__ __align__(16) ushort z2s[64][136];
    __shared__ float b1s[256], b2s[128], w3s[256];
    __shared__ float part3[64][2][2];
    const int tid = threadIdx.x;
    const int wave = tid >> 6, lane = tid & 63;
    const int cc = lane & 15, qd = lane >> 4, lk = qd * 8, rr = qd * 4;
    const int e0 = blockIdx.x * 64;

    b1s[tid] = b1[tid];
    if (tid < 128) b2s[tid] = b2[tid];
    w3s[tid] = w3[tid];
    __syncthreads();

    // stage1: z1 = gelu(U[a] + V[b] + b1), 4 threads/edge, all 16 loads issued up front
    {
        int e = tid >> 2, seg = tid & 3;
        int ge = perm[e0 + e];
        if (ge < 0) ge = 0; if (ge >= M) ge = M - 1;
        int a = dec[(size_t)ge * 2];
        int b = dec[(size_t)ge * 2 + 1];
        if (a < 0) a = 0; if (a >= N_NODES) a = N_NODES - 1;
        if (b < 0) b = 0; if (b >= N_NODES) b = N_NODES - 1;
        const ushort* up = uv + (size_t)a * 512 + seg * 64;
        const ushort* vp = uv + (size_t)b * 512 + 256 + seg * 64;
        short8 us[8], vs[8];
#pragma unroll
        for (int j = 0; j < 8; ++j) us[j] = *(const short8*)(up + j * 8);
#pragma unroll
        for (int j = 0; j < 8; ++j) vs[j] = *(const short8*)(vp + j * 8);
        int d0 = seg * 64;
#pragma unroll
        for (int j = 0; j < 8; ++j) {
            int d = d0 + j * 8;
            short8 zs;
#pragma unroll
            for (int l = 0; l < 8; ++l) {
                float z = b2f((ushort)us[j][l]) + b2f((ushort)vs[j][l]) + b1s[d + l];
                zs[l] = (short)f2b(gelu_fast(z));
            }
            *(short8*)&z1s[e][d] = zs;
        }
    }
    __syncthreads();

    // stage2: [64,256] @ w2t[128][256]^T -> gelu -> z2s [64,128]
    f32x4 acc[4][2];
#pragma unroll
    for (int i = 0; i < 4; ++i)
#pragma unroll
        for (int j = 0; j < 2; ++j) acc[i][j] = (f32x4){0.f, 0.f, 0.f, 0.f};
    const int n0 = wave * 32;
#pragma unroll
    for (int ks = 0; ks < 8; ++ks) {
        short8 af[4], bfv[2];
#pragma unroll
        for (int i = 0; i < 4; ++i) af[i] = *(const short8*)&z1s[i * 16 + cc][ks * 32 + lk];
#pragma unroll
        for (int j = 0; j < 2; ++j)
            bfv[j] = *(const short8*)(w2t + (size_t)(n0 + j * 16 + cc) * 256 + ks * 32 + lk);
#pragma unroll
        for (int i = 0; i < 4; ++i)
#pragma unroll
            for (int j = 0; j < 2; ++j)
                acc[i][j] = __builtin_amdgcn_mfma_f32_16x16x32_bf16(af[i], bfv[j], acc[i][j], 0, 0, 0);
    }
#pragma unroll
    for (int i = 0; i < 4; ++i)
#pragma unroll
        for (int j = 0; j < 2; ++j)
#pragma unroll
            for (int r = 0; r < 4; ++r) {
                int m = i * 16 + rr + r;
                int n = n0 + j * 16 + cc;
                z2s[m][n] = f2b(gelu_fast(acc[i][j][r] + b2s[n]));
            }
    __syncthreads();

    // stage3: [64,128] @ w3[128,2] + b3 — ALL 256 threads: (edge, class, k-half),
    // 8 x short8 vector LDS reads (uniform bank slots), LDS combine.
    {
        int e = tid >> 2, c = tid & 1, hf = (tid >> 1) & 1;
        const ushort* zr = &z2s[e][hf * 64];
        float s = 0.f;
#pragma unroll
        for (int j = 0; j < 8; ++j) {
            short8 v = *(const short8*)(zr + j * 8);
#pragma unroll
            for (int l = 0; l < 8; ++l)
                s += b2f((ushort)v[l]) * w3s[(hf * 64 + j * 8 + l) * 2 + c];
        }
        part3[e][c][hf] = s;
    }
    __syncthreads();
    if (tid < 128) {
        int e = tid >> 1, c = tid & 1;
        float s = part3[e][c][0] + part3[e][c][1] + b3[c];
        int ge = perm[e0 + e];
        if (ge >= 0 && ge < M) outp[(size_t)ge * 2 + c] = s;
    }
}

// ---------------- launch (round-4 structure, 128-row gemm tiles) ----------------
extern "C" void kernel_launch(void* const* d_in, const int* in_sizes, int n_in,
                              void* d_out, int out_size, void* d_ws, size_t ws_size,
                              hipStream_t stream) {
    const float* x          = (const float*)d_in[0];
    const int*   edge_index = (const int*)d_in[1];
    const int*   edge_type  = (const int*)d_in[2];
    const int*   dec_edges  = (const int*)d_in[3];
    const float* W1         = (const float*)d_in[4];
    const float* root1      = (const float*)d_in[5];
    const float* b1         = (const float*)d_in[6];
    const float* W2         = (const float*)d_in[7];
    const float* root2      = (const float*)d_in[8];
    const float* b2         = (const float*)d_in[9];
    const float* ln1_g      = (const float*)d_in[10];
    const float* ln1_b      = (const float*)d_in[11];
    const float* ln2_g      = (const float*)d_in[12];
    const float* ln2_b      = (const float*)d_in[13];
    const float* mlp_w1     = (const float*)d_in[14];
    const float* mlp_b1     = (const float*)d_in[15];
    const float* mlp_w2     = (const float*)d_in[16];
    const float* mlp_b2     = (const float*)d_in[17];
    const float* mlp_w3     = (const float*)d_in[18];
    const float* mlp_b3     = (const float*)d_in[19];

    char* ws = (char*)d_ws;
    size_t off = 0;
    auto alloc = [&](size_t bytes) {
        void* p = ws + off;
        off += (bytes + 255) & ~(size_t)255;
        return p;
    };
    unsigned int* epk     = (unsigned int*)alloc((size_t)E_EDGES * 4);
    unsigned int* sbuf    = (unsigned int*)alloc((size_t)E_EDGES * 4);
    int*          rp2     = (int*)alloc((size_t)(NSEG + 1) * 4);
    int*          hz      = (int*)alloc((size_t)2 * NB2 * 4);
    int*          bh      = hz;
    int*          dh      = hz + NB2;
    int*          bbase   = (int*)alloc((size_t)(NB2 + 1) * 4);
    int*          dbase   = (int*)alloc((size_t)(NB2 + 1) * 4);
    int*          bcur    = (int*)alloc((size_t)NB2 * 4);
    int*          dcur    = (int*)alloc((size_t)NB2 * 4);
    int*          perm    = (int*)alloc((size_t)M_DEC * 4);
    ushort*       B1t     = (ushort*)alloc((size_t)HID * K1 * 2);
    ushort*       B2t     = (ushort*)alloc((size_t)HID * K2 * 2);
    ushort*       wuvt    = (ushort*)alloc((size_t)512 * 256 * 2);
    ushort*       w2t     = (ushort*)alloc((size_t)128 * 256 * 2);
    ushort*       xb      = (ushort*)alloc((size_t)N_NODES * IN_DIM * 2);
    ushort*       hfin    = (ushort*)alloc((size_t)N_NODES * HID * 2);

    size_t regionOff = off;
    ushort* h1ln  = (ushort*)(ws + regionOff);
    ushort* uvbuf = h1ln;
    size_t h1b = (((size_t)N_NODES * HID * 2) + 255) & ~(size_t)255;
    ushort* Achunk = (ushort*)(ws + regionOff + h1b);
    long long chunkB = (long long)ws_size - (long long)(regionOff + h1b);
    int chunk = 64;
    if (chunkB > 0) {
        long long c = chunkB / ((long long)K2 * 2);
        if (c > N_NODES) c = N_NODES;
        c &= ~63LL;
        if (c >= 64) chunk = (int)c;
    }
    int chunk1 = chunk * 2;
    if (chunk1 > N_NODES) chunk1 = N_NODES;

    // two-level bucket sort: coarse count -> 782-scan -> aggregated scatter -> LDS fine sort
    hipMemsetAsync(hz, 0, (size_t)2 * NB2 * 4, stream);
    coarse_count<<<SA_WG, 256, 0, stream>>>(edge_index, dec_edges, bh, dh);
    scan_buckets<<<2, 1024, 0, stream>>>(bh, bbase, bcur, dh, dbase, dcur, rp2);
    stageA<<<SA_WG, 256, 0, stream>>>(edge_index, edge_type, bcur, sbuf, dec_edges, dcur, perm);
    stageB<<<NB2, 512, 0, stream>>>(sbuf, bbase, rp2, epk);

    // merged packs (xconv + enc + mlp)
    {
        int total = N_NODES * IN_DIM / 4 + HID * K1 + HID * K2 + 512 * 256 + 128 * 256;
        pack_all<<<(total + 255) / 256, 256, 0, stream>>>(x, xb, root1, W1, root2, W2,
                                                          B1t, B2t, mlp_w1, mlp_w2, wuvt, w2t);
    }

    // conv1
    for (int n0 = 0; n0 < N_NODES; n0 += chunk1) {
        int m = N_NODES - n0; if (m > chunk1) m = chunk1;
        agg1_kernel<<<(m + 3) / 4, 256, 0, stream>>>(xb, rp2, epk, Achunk, n0, m);
        gemm_fused<<<dim3((m + 127) / 128, 1), 1024, 0, stream>>>(
            Achunk, B1t, K1, m, K1, b1, ln1_g, ln1_b, nullptr, h1ln, HID, n0);
    }
    // conv2 (+h1 residual)
    for (int n0 = 0; n0 < N_NODES; n0 += chunk) {
        int m = N_NODES - n0; if (m > chunk) m = chunk;
        agg2_kernel<<<(m + 3) / 4, 256, 0, stream>>>(h1ln, rp2, epk, Achunk, n0, m);
        gemm_fused<<<dim3((m + 127) / 128, 1), 1024, 0, stream>>>(
            Achunk, B2t, K2, m, K2, b2, ln2_g, ln2_b, h1ln, hfin, HID, n0);
    }

    // U|V = hfin @ [W1_top | W1_bot]
    gemm_fused<<<dim3((N_NODES + 127) / 128, 2), 1024, 0, stream>>>(
        hfin, wuvt, HID, N_NODES, HID, nullptr, nullptr, nullptr, nullptr, uvbuf, 512, 0);

    // edge decode
    edge_kernel<<<(M_DEC + 63) / 64, 256, 0, stream>>>(
        uvbuf, dec_edges, perm, mlp_b1, w2t, mlp_b2, mlp_w3, mlp_b3, (float*)d_out, M_DEC);
}

// Round 9
// 698.875 us; speedup vs baseline: 1.0473x; 1.0473x over previous
//
#include <hip/hip_runtime.h>
#include <math.h>

typedef __attribute__((ext_vector_type(8))) short short8;
typedef __attribute__((ext_vector_type(4))) float f32x4;
typedef __attribute__((address_space(3))) void lds_void;
typedef const __attribute__((address_space(1))) void glb_void;

#define N_NODES 50000
#define NUM_REL 8
#define IN_DIM 128
#define HID 256
#define E_EDGES 1600000
#define M_DEC 200000
#define K1 1152
#define K2 2304
#define LN_EPS 1e-5f
#define NSEG (N_NODES * 8)            /* per-(node,rel) segments */
#define NB2 782                       /* coarse buckets = ceil(N/64) */
#define SA_WG 391                     /* ceil(E/4096) */
#define SA_CH 4096
#define SA_DCH 512

#define RFL(x) __builtin_amdgcn_readfirstlane(x)

__device__ __forceinline__ float b2f(ushort u) {
    union { unsigned int i; float f; } v; v.i = ((unsigned int)u) << 16; return v.f;
}
__device__ __forceinline__ ushort f2b(float f) {
    union { float f; unsigned int i; } v; v.f = f;
    unsigned int r = v.i + 0x7FFFu + ((v.i >> 16) & 1u);
    return (ushort)(r >> 16);
}
__device__ __forceinline__ unsigned int pk2(ushort a, ushort b) {
    return (unsigned int)a | ((unsigned int)b << 16);
}
// fast gelu (tanh form, native exp/rcp): |err| <= ~3e-3 absolute, fine at 2% rel tol
__device__ __forceinline__ float gelu_fast(float x) {
    float y = 1.5957691216f * (x + 0.044715f * x * x * x);   // 2*sqrt(2/pi)*(...)
    float e = __expf(y);
    float t = 1.f - 2.f * __builtin_amdgcn_rcpf(e + 1.f);
    return 0.5f * x * (1.f + t);
}
__device__ __forceinline__ int clampn(int v) {
    if ((unsigned)v >= N_NODES) v = (v < 0) ? 0 : N_NODES - 1;
    return v;
}

// ================= two-level bucket sort (no per-edge global atomics) =================

__global__ __launch_bounds__(256) void coarse_count(const int* __restrict__ ei,
                                                    const int* __restrict__ dec,
                                                    int* __restrict__ bh, int* __restrict__ dh) {
    __shared__ int lb[NB2], ld[NB2];
    const int t = threadIdx.x;
    for (int i = t; i < NB2; i += 256) { lb[i] = 0; ld[i] = 0; }
    __syncthreads();
    const int e0 = blockIdx.x * SA_CH;
#pragma unroll
    for (int k = 0; k < 16; ++k) {
        int e = e0 + k * 256 + t;
        if (e < E_EDGES) {
            int dst = clampn(ei[E_EDGES + e]);
            atomicAdd(&lb[dst >> 6], 1);
        }
    }
    const int d0 = blockIdx.x * SA_DCH;
#pragma unroll
    for (int k = 0; k < 2; ++k) {
        int i = d0 + k * 256 + t;
        if (i < M_DEC) {
            int a = clampn(dec[(size_t)i * 2]);
            atomicAdd(&ld[a >> 6], 1);
        }
    }
    __syncthreads();
    for (int i = t; i < NB2; i += 256) {
        if (lb[i]) atomicAdd(&bh[i], lb[i]);
        if (ld[i]) atomicAdd(&dh[i], ld[i]);
    }
}

__global__ __launch_bounds__(1024) void scan_buckets(const int* __restrict__ bh, int* __restrict__ bbase,
                                                     int* __restrict__ bcur,
                                                     const int* __restrict__ dh, int* __restrict__ dbase,
                                                     int* __restrict__ dcur, int* __restrict__ rp2) {
    __shared__ int ts[1024];
    const int t = threadIdx.x;
    const int* src = (blockIdx.x == 0) ? bh : dh;
    int* ob = (blockIdx.x == 0) ? bbase : dbase;
    int* oc = (blockIdx.x == 0) ? bcur : dcur;
    int v = (t < NB2) ? src[t] : 0;
    ts[t] = v;
    __syncthreads();
#pragma unroll
    for (int off = 1; off < 1024; off <<= 1) {
        int u = (t >= off) ? ts[t - off] : 0;
        __syncthreads();
        ts[t] += u;
        __syncthreads();
    }
    if (t < NB2) { int ex = ts[t] - v; ob[t] = ex; oc[t] = ex; }
    if (t == NB2 - 1) ob[NB2] = ts[t];
    if (t == 0 && blockIdx.x == 0) rp2[NSEG] = E_EDGES;
}

__global__ __launch_bounds__(256) void stageA(const int* __restrict__ ei, const int* __restrict__ et,
                                              int* __restrict__ bcur, unsigned int* __restrict__ sbuf,
                                              const int* __restrict__ dec, int* __restrict__ dcur,
                                              int* __restrict__ perm) {
    __shared__ int h[NB2], base_[NB2];
    const int t = threadIdx.x;
    const int e0 = blockIdx.x * SA_CH;
    for (int i = t; i < NB2; i += 256) h[i] = 0;
    __syncthreads();
    int myb[16];
#pragma unroll
    for (int k = 0; k < 16; ++k) {
        int e = e0 + k * 256 + t;
        int b = -1;
        if (e < E_EDGES) {
            int dst = clampn(ei[E_EDGES + e]);
            b = dst >> 6;
            atomicAdd(&h[b], 1);
        }
        myb[k] = b;
    }
    __syncthreads();
    for (int i = t; i < NB2; i += 256) {
        int c = h[i];
        base_[i] = c ? atomicAdd(&bcur[i], c) : 0;
    }
    __syncthreads();
    for (int i = t; i < NB2; i += 256) h[i] = 0;
    __syncthreads();
#pragma unroll
    for (int k = 0; k < 16; ++k) {
        int e = e0 + k * 256 + t;
        int b = myb[k];
        if (b >= 0) {
            int dst = clampn(ei[E_EDGES + e]);
            int src = clampn(ei[e]);
            int r = et[e] & 7;
            int off = atomicAdd(&h[b], 1);
            sbuf[base_[b] + off] =
                (unsigned)src | ((unsigned)r << 16) | ((unsigned)(dst & 63) << 19);
        }
    }
    // ---- decode perm bucketing ----
    __syncthreads();
    for (int i = t; i < NB2; i += 256) h[i] = 0;
    __syncthreads();
    const int d0 = blockIdx.x * SA_DCH;
    int dbk[2];
#pragma unroll
    for (int k = 0; k < 2; ++k) {
        int i = d0 + k * 256 + t;
        int b = -1;
        if (i < M_DEC) {
            int a = clampn(dec[(size_t)i * 2]);
            b = a >> 6;
            atomicAdd(&h[b], 1);
        }
        dbk[k] = b;
    }
    __syncthreads();
    for (int i = t; i < NB2; i += 256) {
        int c = h[i];
        base_[i] = c ? atomicAdd(&dcur[i], c) : 0;
    }
    __syncthreads();
    for (int i = t; i < NB2; i += 256) h[i] = 0;
    __syncthreads();
#pragma unroll
    for (int k = 0; k < 2; ++k) {
        int i = d0 + k * 256 + t;
        int b = dbk[k];
        if (b >= 0) {
            int off = atomicAdd(&h[b], 1);
            perm[base_[b] + off] = i;
        }
    }
}

__global__ __launch_bounds__(512) void stageB(const unsigned int* __restrict__ sbuf,
                                              const int* __restrict__ bbase,
                                              int* __restrict__ rp2,
                                              unsigned int* __restrict__ epk) {
    __shared__ int cnt[512];
    __shared__ int pref[512];
    const int t = threadIdx.x;
    const int b = blockIdx.x;
    const int s0 = bbase[b], s1 = bbase[b + 1];
    cnt[t] = 0;
    __syncthreads();
    for (int i = s0 + t; i < s1; i += 512) {
        unsigned int p = sbuf[i];
        int ls = (((p >> 19) & 63) << 3) | ((p >> 16) & 7);
        atomicAdd(&cnt[ls], 1);
    }
    __syncthreads();
    pref[t] = cnt[t];
    __syncthreads();
#pragma unroll
    for (int off = 1; off < 512; off <<= 1) {
        int u = (t >= off) ? pref[t - off] : 0;
        __syncthreads();
        pref[t] += u;
        __syncthreads();
    }
    int excl = pref[t] - cnt[t];
    int seg = b * 512 + t;
    if (seg < NSEG) rp2[seg] = s0 + excl;
    __syncthreads();
    pref[t] = excl;
    cnt[t] = 0;
    __syncthreads();
    for (int i = s0 + t; i < s1; i += 512) {
        unsigned int p = sbuf[i];
        int ls = (((p >> 19) & 63) << 3) | ((p >> 16) & 7);
        int off = atomicAdd(&cnt[ls], 1);
        epk[s0 + pref[ls] + off] = p & 0xFFFFu;
    }
}

// ---------------- merged pack: xconv + enc weights + mlp weights ----------------
__global__ void pack_all(const float* __restrict__ x, ushort* __restrict__ xb,
                         const float* __restrict__ root1, const float* __restrict__ W1,
                         const float* __restrict__ root2, const float* __restrict__ W2,
                         ushort* __restrict__ B1t, ushort* __restrict__ B2t,
                         const float* __restrict__ mw1, const float* __restrict__ mw2,
                         ushort* __restrict__ wuvt, ushort* __restrict__ w2t) {
    const int XC = N_NODES * IN_DIM / 4;
    const int N1 = HID * K1;
    const int N2 = HID * K2;
    const int NU = 512 * 256;
    const int NW = 128 * 256;
    int idx = blockIdx.x * 256 + threadIdx.x;
    if (idx < XC) {
        float4 v = *(const float4*)(x + (size_t)idx * 4);
        uint2 o;
        o.x = pk2(f2b(v.x), f2b(v.y));
        o.y = pk2(f2b(v.z), f2b(v.w));
        *(uint2*)(xb + (size_t)idx * 4) = o;
        return;
    }
    idx -= XC;
    if (idx < N1) {
        int n = idx / K1, k = idx % K1;
        float v;
        if (k < IN_DIM) v = root1[k * HID + n];
        else { int kk = k - IN_DIM; v = W1[(size_t)(kk >> 7) * IN_DIM * HID + (kk & 127) * HID + n]; }
        B1t[(size_t)n * K1 + k] = f2b(v);
        return;
    }
    idx -= N1;
    if (idx < N2) {
        int n = idx / K2, k = idx % K2;
        float v;
        if (k < HID) v = root2[k * HID + n];
        else { int kk = k - HID; v = W2[(size_t)(kk >> 8) * HID * HID + (kk & 255) * HID + n]; }
        B2t[(size_t)n * K2 + k] = f2b(v);
        return;
    }
    idx -= N2;
    if (idx < NU) {
        int n = idx / 256, k = idx % 256;
        float v = (n < 256) ? mw1[(size_t)k * 256 + n] : mw1[(size_t)(256 + k) * 256 + (n - 256)];
        wuvt[(size_t)n * 256 + k] = f2b(v);
        return;
    }
    idx -= NU;
    if (idx < NW) {
        int n = idx / 256, k = idx % 256;
        w2t[n * 256 + k] = f2b(mw2[k * 128 + n]);
    }
}

// ---------------- aggregation: wave-per-node, SCALARIZED segment bookkeeping ----------
// All rp[]/epk[] values are wave-uniform; readfirstlane pins them to SGPRs so epk
// reads become s_load (SMEM pipe, no per-lane VMEM broadcast) and gather addresses
// become SALU-mul + one VALU add. Semantically identity.

#define FL1() { int c_ = segend - segbeg; float inv_ = c_ > 0 ? 1.f / (float)c_ : 0.f; \
    *(unsigned int*)(Arow + IN_DIM + r * IN_DIM + 2 * lane) = \
        pk2(f2b((aA.x + aB.x) * inv_), f2b((aA.y + aB.y) * inv_)); \
    aA.x = 0.f; aA.y = 0.f; aB.x = 0.f; aB.y = 0.f; \
    ++r; segbeg = segend; segend = (r < 8) ? RFL(rp[r + 1]) : end; \
    if (segend < segbeg) segend = segbeg; if (segend > end) segend = end; }
#define CK1(EI) { while (r < 8 && (EI) >= segend) FL1(); }
#define AC1A(U) { aA.x += b2f((ushort)((U) & 0xFFFFu)); aA.y += b2f((ushort)((U) >> 16)); }
#define AC1B(U) { aB.x += b2f((ushort)((U) & 0xFFFFu)); aB.y += b2f((ushort)((U) >> 16)); }

__global__ __launch_bounds__(256) void agg1_kernel(const ushort* __restrict__ xb,
                                                   const int* __restrict__ rp2,
                                                   const unsigned int* __restrict__ epk,
                                                   ushort* __restrict__ Achunk, int n0, int m) {
    const int w = threadIdx.x >> 6, lane = threadIdx.x & 63;
    const int local = blockIdx.x * 4 + w;
    if (local >= m) return;
    const int n = n0 + local;
    const int* rp = rp2 + n * 8;
    ushort* Arow = Achunk + (size_t)local * K1;
    const ushort* xbb = xb + 2 * lane;
    *(unsigned int*)(Arow + 2 * lane) = *(const unsigned int*)(xb + (size_t)n * IN_DIM + 2 * lane);

    int beg = RFL(rp[0]), end = RFL(rp[8]);
    if (beg < 0) beg = 0;
    if (end > E_EDGES) end = E_EDGES;
    if (end < beg) end = beg;

    float2 aA = {0.f, 0.f}, aB = {0.f, 0.f};
    int r = 0, segbeg = beg, segend = RFL(rp[1]);
    if (segend < segbeg) segend = segbeg; if (segend > end) segend = end;

    int e = beg;
    for (; e + 7 < end; e += 8) {
        unsigned int p0 = RFL(epk[e]),     p1 = RFL(epk[e + 1]);
        unsigned int p2 = RFL(epk[e + 2]), p3 = RFL(epk[e + 3]);
        unsigned int p4 = RFL(epk[e + 4]), p5 = RFL(epk[e + 5]);
        unsigned int p6 = RFL(epk[e + 6]), p7 = RFL(epk[e + 7]);
        unsigned int u0 = *(const unsigned int*)(xbb + (size_t)p0 * IN_DIM);
        unsigned int u1 = *(const unsigned int*)(xbb + (size_t)p1 * IN_DIM);
        unsigned int u2 = *(const unsigned int*)(xbb + (size_t)p2 * IN_DIM);
        unsigned int u3 = *(const unsigned int*)(xbb + (size_t)p3 * IN_DIM);
        unsigned int u4 = *(const unsigned int*)(xbb + (size_t)p4 * IN_DIM);
        unsigned int u5 = *(const unsigned int*)(xbb + (size_t)p5 * IN_DIM);
        unsigned int u6 = *(const unsigned int*)(xbb + (size_t)p6 * IN_DIM);
        unsigned int u7 = *(const unsigned int*)(xbb + (size_t)p7 * IN_DIM);
        CK1(e)     AC1A(u0) CK1(e + 1) AC1B(u1)
        CK1(e + 2) AC1A(u2) CK1(e + 3) AC1B(u3)
        CK1(e + 4) AC1A(u4) CK1(e + 5) AC1B(u5)
        CK1(e + 6) AC1A(u6) CK1(e + 7) AC1B(u7)
    }
    for (; e < end; ++e) {
        unsigned int p = RFL(epk[e]);
        unsigned int u = *(const unsigned int*)(xbb + (size_t)p * IN_DIM);
        CK1(e) AC1A(u)
    }
    while (r < 8) FL1();
}

#define FL2() { int c_ = segend - segbeg; float inv_ = c_ > 0 ? 1.f / (float)c_ : 0.f; \
    f32x4 t_ = aA + aB; uint2 o_; \
    o_.x = pk2(f2b(t_[0] * inv_), f2b(t_[1] * inv_)); \
    o_.y = pk2(f2b(t_[2] * inv_), f2b(t_[3] * inv_)); \
    *(uint2*)(Arow + HID + r * HID + 4 * lane) = o_; \
    aA = (f32x4){0.f, 0.f, 0.f, 0.f}; aB = aA; \
    ++r; segbeg = segend; segend = (r < 8) ? RFL(rp[r + 1]) : end; \
    if (segend < segbeg) segend = segbeg; if (segend > end) segend = end; }
#define CK2(EI) { while (r < 8 && (EI) >= segend) FL2(); }
#define AC2A(U) { f32x4 f_; \
    f_[0] = b2f((ushort)((U).x & 0xFFFFu)); f_[1] = b2f((ushort)((U).x >> 16)); \
    f_[2] = b2f((ushort)((U).y & 0xFFFFu)); f_[3] = b2f((ushort)((U).y >> 16)); aA += f_; }
#define AC2B(U) { f32x4 f_; \
    f_[0] = b2f((ushort)((U).x & 0xFFFFu)); f_[1] = b2f((ushort)((U).x >> 16)); \
    f_[2] = b2f((ushort)((U).y & 0xFFFFu)); f_[3] = b2f((ushort)((U).y >> 16)); aB += f_; }

__global__ __launch_bounds__(256) void agg2_kernel(const ushort* __restrict__ h1,
                                                   const int* __restrict__ rp2,
                                                   const unsigned int* __restrict__ epk,
                                                   ushort* __restrict__ Achunk, int n0, int m) {
    const int w = threadIdx.x >> 6, lane = threadIdx.x & 63;
    const int local = blockIdx.x * 4 + w;
    if (local >= m) return;
    const int n = n0 + local;
    const int* rp = rp2 + n * 8;
    ushort* Arow = Achunk + (size_t)local * K2;
    const ushort* hb = h1 + 4 * lane;
    *(uint2*)(Arow + 4 * lane) = *(const uint2*)(h1 + (size_t)n * HID + 4 * lane);

    int beg = RFL(rp[0]), end = RFL(rp[8]);
    if (beg < 0) beg = 0;
    if (end > E_EDGES) end = E_EDGES;
    if (end < beg) end = beg;

    f32x4 aA = {0.f, 0.f, 0.f, 0.f}, aB = {0.f, 0.f, 0.f, 0.f};
    int r = 0, segbeg = beg, segend = RFL(rp[1]);
    if (segend < segbeg) segend = segbeg; if (segend > end) segend = end;

    int e = beg;
    for (; e + 7 < end; e += 8) {
        unsigned int p0 = RFL(epk[e]),     p1 = RFL(epk[e + 1]);
        unsigned int p2 = RFL(epk[e + 2]), p3 = RFL(epk[e + 3]);
        unsigned int p4 = RFL(epk[e + 4]), p5 = RFL(epk[e + 5]);
        unsigned int p6 = RFL(epk[e + 6]), p7 = RFL(epk[e + 7]);
        uint2 u0 = *(const uint2*)(hb + (size_t)p0 * HID);
        uint2 u1 = *(const uint2*)(hb + (size_t)p1 * HID);
        uint2 u2 = *(const uint2*)(hb + (size_t)p2 * HID);
        uint2 u3 = *(const uint2*)(hb + (size_t)p3 * HID);
        uint2 u4 = *(const uint2*)(hb + (size_t)p4 * HID);
        uint2 u5 = *(const uint2*)(hb + (size_t)p5 * HID);
        uint2 u6 = *(const uint2*)(hb + (size_t)p6 * HID);
        uint2 u7 = *(const uint2*)(hb + (size_t)p7 * HID);
        CK2(e)     AC2A(u0) CK2(e + 1) AC2B(u1)
        CK2(e + 2) AC2A(u2) CK2(e + 3) AC2B(u3)
        CK2(e + 4) AC2A(u4) CK2(e + 5) AC2B(u5)
        CK2(e + 6) AC2A(u6) CK2(e + 7) AC2B(u7)
    }
    for (; e < end; ++e) {
        unsigned int p = RFL(epk[e]);
        uint2 u = *(const uint2*)(hb + (size_t)p * HID);
        CK2(e) AC2A(u)
    }
    while (r < 8) FL2();
}

// ---------------- GEMM 64x256 tile, 512 thr, double-buffered LDS, counted vmcnt ----------
// VERIFIED round-4 config (704 us). 3-buffer/128-tile/fusion all regressed — do not touch.

#define STAGE(BUF, KO) { \
    __builtin_amdgcn_global_load_lds((glb_void*)(Ab + (KO)), \
        (lds_void*)(AsBase + (BUF) * 4096 + wave * 8 * 64), 16, 0, 0); \
    _Pragma("unroll") \
    for (int j_ = 0; j_ < 4; ++j_) \
        __builtin_amdgcn_global_load_lds((glb_void*)(Bb + (size_t)j_ * 8 * K + (KO)), \
            (lds_void*)(BsBase + (BUF) * 16384 + (wave * 32 + j_ * 8) * 64), 16, 0, 0); }

#define COMPUTE(CUR) { \
    _Pragma("unroll") \
    for (int kk = 0; kk < 2; ++kk) { \
        const int gsw = (((kk * 4 + qd) ^ (cc & 7)) * 8); \
        short8 af[2], bfv[4]; \
        _Pragma("unroll") \
        for (int i = 0; i < 2; ++i) \
            af[i] = *(const short8*)&AsBase[(CUR) * 4096 + (mh * 32 + i * 16 + cc) * 64 + gsw]; \
        _Pragma("unroll") \
        for (int j = 0; j < 4; ++j) \
            bfv[j] = *(const short8*)&BsBase[(CUR) * 16384 + (wn + j * 16 + cc) * 64 + gsw]; \
        _Pragma("unroll") \
        for (int i = 0; i < 2; ++i) \
            _Pragma("unroll") \
            for (int j = 0; j < 4; ++j) \
                acc[i][j] = __builtin_amdgcn_mfma_f32_16x16x32_bf16(af[i], bfv[j], acc[i][j], 0, 0, 0); \
    } }

__global__ __launch_bounds__(512, 4) void gemm_fused(
    const ushort* __restrict__ A, const ushort* __restrict__ Bt,
    int lda, int M, int K,
    const float* __restrict__ bias, const float* __restrict__ g,
    const float* __restrict__ bvec, const ushort* __restrict__ resid,
    ushort* __restrict__ outp, int ldc, int rowOff) {
    __shared__ __align__(16) ushort smem[40960];  // 80 KB: As[2][64*64] | Bs[2][256*64]
    ushort* AsBase = smem;
    ushort* BsBase = smem + 2 * 64 * 64;
    const int tid = threadIdx.x;
    const int wave = tid >> 6, lane = tid & 63;
    const int w4 = wave & 3, mh = wave >> 2;
    const int cc = lane & 15, qd = lane >> 4;
    const int row0 = blockIdx.x * 64;
    const int colBase = blockIdx.y * 256;
    const int wn = w4 * 64;
    const int srow = lane >> 3;
    const int sgrp = (lane & 7) ^ (srow & 7);
    f32x4 acc[2][4];
#pragma unroll
    for (int i = 0; i < 2; ++i)
#pragma unroll
        for (int j = 0; j < 4; ++j) acc[i][j] = (f32x4){0.f, 0.f, 0.f, 0.f};

    const ushort* Ab = A + (size_t)(row0 + wave * 8 + srow) * lda + sgrp * 8;
    const ushort* Bb = Bt + (size_t)(colBase + wave * 32 + srow) * K + sgrp * 8;

    STAGE(0, 0)
    for (int k0 = 0; k0 < K; k0 += 128) {
        if (k0 + 64 < K) {
            STAGE(1, k0 + 64)
            asm volatile("s_waitcnt vmcnt(5)" ::: "memory");
        } else {
            asm volatile("s_waitcnt vmcnt(0)" ::: "memory");
        }
        __builtin_amdgcn_s_barrier();
        COMPUTE(0)
        asm volatile("s_waitcnt lgkmcnt(0)" ::: "memory");
        __builtin_amdgcn_s_barrier();

        if (k0 + 128 < K) {
            STAGE(0, k0 + 128)
            asm volatile("s_waitcnt vmcnt(5)" ::: "memory");
        } else {
            asm volatile("s_waitcnt vmcnt(0)" ::: "memory");
        }
        __builtin_amdgcn_s_barrier();
        COMPUTE(1)
        asm volatile("s_waitcnt lgkmcnt(0)" ::: "memory");
        __builtin_amdgcn_s_barrier();
    }

    if (g) {
        float* partS = (float*)smem;          // [64][4] aliases dead staging LDS
        float* partQ = (float*)smem + 256;    // [64][4]
        float* muS   = (float*)smem + 512;    // [64]
        float* rsS   = (float*)smem + 576;    // [64]
#pragma unroll
        for (int j = 0; j < 4; ++j) {
            float bcol = bias[wn + j * 16 + cc];
#pragma unroll
            for (int i = 0; i < 2; ++i)
#pragma unroll
                for (int r = 0; r < 4; ++r)
                    acc[i][j][r] = fmaxf(acc[i][j][r] + bcol, 0.f);
        }
#pragma unroll
        for (int i = 0; i < 2; ++i)
#pragma unroll
            for (int r = 0; r < 4; ++r) {
                float s = acc[i][0][r] + acc[i][1][r] + acc[i][2][r] + acc[i][3][r];
                float q = acc[i][0][r] * acc[i][0][r] + acc[i][1][r] * acc[i][1][r]
                        + acc[i][2][r] * acc[i][2][r] + acc[i][3][r] * acc[i][3][r];
#pragma unroll
                for (int off = 1; off <= 8; off <<= 1) {
                    s += __shfl_xor(s, off, 64);
                    q += __shfl_xor(q, off, 64);
                }
                if (cc == 0) {
                    int row = mh * 32 + i * 16 + qd * 4 + r;
                    partS[row * 4 + w4] = s;
                    partQ[row * 4 + w4] = q;
                }
            }
        __syncthreads();
        if (tid < 64) {
            float S = partS[tid * 4] + partS[tid * 4 + 1] + partS[tid * 4 + 2] + partS[tid * 4 + 3];
            float Q = partQ[tid * 4] + partQ[tid * 4 + 1] + partQ[tid * 4 + 2] + partQ[tid * 4 + 3];
            float mu = S * (1.f / 256.f);
            float var = Q * (1.f / 256.f) - mu * mu;
            muS[tid] = mu;
            rsS[tid] = rsqrtf(fmaxf(var, 0.f) + LN_EPS);
        }
        __syncthreads();
#pragma unroll
        for (int i = 0; i < 2; ++i)
#pragma unroll
            for (int r = 0; r < 4; ++r) {
                int row = mh * 32 + i * 16 + qd * 4 + r;
                int grow = row0 + row;
                if (grow >= M) continue;
                float mu = muS[row], rs = rsS[row];
                size_t base = (size_t)(rowOff + grow) * ldc;
#pragma unroll
                for (int j = 0; j < 4; ++j) {
                    int col = wn + j * 16 + cc;
                    float val = (acc[i][j][r] - mu) * rs * g[col] + bvec[col];
                    if (resid) val += b2f(resid[base + col]);
                    outp[base + col] = f2b(val);
                }
            }
    } else {
#pragma unroll
        for (int i = 0; i < 2; ++i)
#pragma unroll
            for (int r = 0; r < 4; ++r) {
                int grow = row0 + mh * 32 + i * 16 + qd * 4 + r;
                if (grow >= M) continue;
                size_t base = (size_t)(rowOff + grow) * ldc;
#pragma unroll
                for (int j = 0; j < 4; ++j) {
                    int col = colBase + wn + j * 16 + cc;
                    outp[base + col] = f2b(acc[i][j][r]);
                }
            }
    }
}

// ---------------- edge decode: parallel vectorized stage3 (bank-conflict fix) ------------
__global__ __launch_bounds__(256) void edge_kernel(
    const ushort* __restrict__ uv, const int* __restrict__ dec, const int* __restrict__ perm,
    const float* __restrict__ b1, const ushort* __restrict__ w2t,
    const float* __restrict__ b2, const float* __restrict__ w3,
    const float* __restrict__ b3, float* __restrict__ outp, int M) {
    __shared__ __align__(16) ushort z1s[64][264];
    __shared__ __align__(16) ushort z2s[64][136];
    __shared__ float b1s[256], b2s[128], w3s[256];
    __shared__ float part3[64][2][2];
    const int tid = threadIdx.x;
    const int wave = tid >> 6, lane = tid & 63;
    const int cc = lane & 15, qd = lane >> 4, lk = qd * 8, rr = qd * 4;
    const int e0 = blockIdx.x * 64;

    b1s[tid] = b1[tid];
    if (tid < 128) b2s[tid] = b2[tid];
    w3s[tid] = w3[tid];
    __syncthreads();

    // stage1: z1 = gelu(U[a] + V[b] + b1), 4 threads/edge, all 16 loads issued up front
    {
        int e = tid >> 2, seg = tid & 3;
        int ge = perm[e0 + e];
        if (ge < 0) ge = 0; if (ge >= M) ge = M - 1;
        int a = dec[(size_t)ge * 2];
        int b = dec[(size_t)ge * 2 + 1];
        if (a < 0) a = 0; if (a >= N_NODES) a = N_NODES - 1;
        if (b < 0) b = 0; if (b >= N_NODES) b = N_NODES - 1;
        const ushort* up = uv + (size_t)a * 512 + seg * 64;
        const ushort* vp = uv + (size_t)b * 512 + 256 + seg * 64;
        short8 us[8], vs[8];
#pragma unroll
        for (int j = 0; j < 8; ++j) us[j] = *(const short8*)(up + j * 8);
#pragma unroll
        for (int j = 0; j < 8; ++j) vs[j] = *(const short8*)(vp + j * 8);
        int d0 = seg * 64;
#pragma unroll
        for (int j = 0; j < 8; ++j) {
            int d = d0 + j * 8;
            short8 zs;
#pragma unroll
            for (int l = 0; l < 8; ++l) {
                float z = b2f((ushort)us[j][l]) + b2f((ushort)vs[j][l]) + b1s[d + l];
                zs[l] = (short)f2b(gelu_fast(z));
            }
            *(short8*)&z1s[e][d] = zs;
        }
    }
    __syncthreads();

    // stage2: [64,256] @ w2t[128][256]^T -> gelu -> z2s [64,128]
    f32x4 acc[4][2];
#pragma unroll
    for (int i = 0; i < 4; ++i)
#pragma unroll
        for (int j = 0; j < 2; ++j) acc[i][j] = (f32x4){0.f, 0.f, 0.f, 0.f};
    const int n0 = wave * 32;
#pragma unroll
    for (int ks = 0; ks < 8; ++ks) {
        short8 af[4], bfv[2];
#pragma unroll
        for (int i = 0; i < 4; ++i) af[i] = *(const short8*)&z1s[i * 16 + cc][ks * 32 + lk];
#pragma unroll
        for (int j = 0; j < 2; ++j)
            bfv[j] = *(const short8*)(w2t + (size_t)(n0 + j * 16 + cc) * 256 + ks * 32 + lk);
#pragma unroll
        for (int i = 0; i < 4; ++i)
#pragma unroll
            for (int j = 0; j < 2; ++j)
                acc[i][j] = __builtin_amdgcn_mfma_f32_16x16x32_bf16(af[i], bfv[j], acc[i][j], 0, 0, 0);
    }
#pragma unroll
    for (int i = 0; i < 4; ++i)
#pragma unroll
        for (int j = 0; j < 2; ++j)
#pragma unroll
            for (int r = 0; r < 4; ++r) {
                int m = i * 16 + rr + r;
                int n = n0 + j * 16 + cc;
                z2s[m][n] = f2b(gelu_fast(acc[i][j][r] + b2s[n]));
            }
    __syncthreads();

    // stage3: [64,128] @ w3[128,2] + b3 — ALL 256 threads: (edge, class, k-half),
    // 8 x short8 vector LDS reads (uniform bank slots), LDS combine.
    {
        int e = tid >> 2, c = tid & 1, hf = (tid >> 1) & 1;
        const ushort* zr = &z2s[e][hf * 64];
        float s = 0.f;
#pragma unroll
        for (int j = 0; j < 8; ++j) {
            short8 v = *(const short8*)(zr + j * 8);
#pragma unroll
            for (int l = 0; l < 8; ++l)
                s += b2f((ushort)v[l]) * w3s[(hf * 64 + j * 8 + l) * 2 + c];
        }
        part3[e][c][hf] = s;
    }
    __syncthreads();
    if (tid < 128) {
        int e = tid >> 1, c = tid & 1;
        float s = part3[e][c][0] + part3[e][c][1] + b3[c];
        int ge = perm[e0 + e];
        if (ge >= 0 && ge < M) outp[(size_t)ge * 2 + c] = s;
    }
}

// ---------------- launch (round-4 structure) ----------------
extern "C" void kernel_launch(void* const* d_in, const int* in_sizes, int n_in,
                              void* d_out, int out_size, void* d_ws, size_t ws_size,
                              hipStream_t stream) {
    const float* x          = (const float*)d_in[0];
    const int*   edge_index = (const int*)d_in[1];
    const int*   edge_type  = (const int*)d_in[2];
    const int*   dec_edges  = (const int*)d_in[3];
    const float* W1         = (const float*)d_in[4];
    const float* root1      = (const float*)d_in[5];
    const float* b1         = (const float*)d_in[6];
    const float* W2         = (const float*)d_in[7];
    const float* root2      = (const float*)d_in[8];
    const float* b2         = (const float*)d_in[9];
    const float* ln1_g      = (const float*)d_in[10];
    const float* ln1_b      = (const float*)d_in[11];
    const float* ln2_g      = (const float*)d_in[12];
    const float* ln2_b      = (const float*)d_in[13];
    const float* mlp_w1     = (const float*)d_in[14];
    const float* mlp_b1     = (const float*)d_in[15];
    const float* mlp_w2     = (const float*)d_in[16];
    const float* mlp_b2     = (const float*)d_in[17];
    const float* mlp_w3     = (const float*)d_in[18];
    const float* mlp_b3     = (const float*)d_in[19];

    char* ws = (char*)d_ws;
    size_t off = 0;
    auto alloc = [&](size_t bytes) {
        void* p = ws + off;
        off += (bytes + 255) & ~(size_t)255;
        return p;
    };
    unsigned int* epk     = (unsigned int*)alloc((size_t)E_EDGES * 4);
    unsigned int* sbuf    = (unsigned int*)alloc((size_t)E_EDGES * 4);
    int*          rp2     = (int*)alloc((size_t)(NSEG + 1) * 4);
    int*          hz      = (int*)alloc((size_t)2 * NB2 * 4);
    int*          bh      = hz;
    int*          dh      = hz + NB2;
    int*          bbase   = (int*)alloc((size_t)(NB2 + 1) * 4);
    int*          dbase   = (int*)alloc((size_t)(NB2 + 1) * 4);
    int*          bcur    = (int*)alloc((size_t)NB2 * 4);
    int*          dcur    = (int*)alloc((size_t)NB2 * 4);
    int*          perm    = (int*)alloc((size_t)M_DEC * 4);
    ushort*       B1t     = (ushort*)alloc((size_t)HID * K1 * 2);
    ushort*       B2t     = (ushort*)alloc((size_t)HID * K2 * 2);
    ushort*       wuvt    = (ushort*)alloc((size_t)512 * 256 * 2);
    ushort*       w2t     = (ushort*)alloc((size_t)128 * 256 * 2);
    ushort*       xb      = (ushort*)alloc((size_t)N_NODES * IN_DIM * 2);
    ushort*       hfin    = (ushort*)alloc((size_t)N_NODES * HID * 2);

    size_t regionOff = off;
    ushort* h1ln  = (ushort*)(ws + regionOff);
    ushort* uvbuf = h1ln;
    size_t h1b = (((size_t)N_NODES * HID * 2) + 255) & ~(size_t)255;
    ushort* Achunk = (ushort*)(ws + regionOff + h1b);
    long long chunkB = (long long)ws_size - (long long)(regionOff + h1b);
    int chunk = 64;
    if (chunkB > 0) {
        long long c = chunkB / ((long long)K2 * 2);
        if (c > N_NODES) c = N_NODES;
        c &= ~63LL;
        if (c >= 64) chunk = (int)c;
    }
    int chunk1 = chunk * 2;
    if (chunk1 > N_NODES) chunk1 = N_NODES;

    // two-level bucket sort: coarse count -> 782-scan -> aggregated scatter -> LDS fine sort
    hipMemsetAsync(hz, 0, (size_t)2 * NB2 * 4, stream);
    coarse_count<<<SA_WG, 256, 0, stream>>>(edge_index, dec_edges, bh, dh);
    scan_buckets<<<2, 1024, 0, stream>>>(bh, bbase, bcur, dh, dbase, dcur, rp2);
    stageA<<<SA_WG, 256, 0, stream>>>(edge_index, edge_type, bcur, sbuf, dec_edges, dcur, perm);
    stageB<<<NB2, 512, 0, stream>>>(sbuf, bbase, rp2, epk);

    // merged packs (xconv + enc + mlp)
    {
        int total = N_NODES * IN_DIM / 4 + HID * K1 + HID * K2 + 512 * 256 + 128 * 256;
        pack_all<<<(total + 255) / 256, 256, 0, stream>>>(x, xb, root1, W1, root2, W2,
                                                          B1t, B2t, mlp_w1, mlp_w2, wuvt, w2t);
    }

    // conv1
    for (int n0 = 0; n0 < N_NODES; n0 += chunk1) {
        int m = N_NODES - n0; if (m > chunk1) m = chunk1;
        agg1_kernel<<<(m + 3) / 4, 256, 0, stream>>>(xb, rp2, epk, Achunk, n0, m);
        gemm_fused<<<dim3((m + 63) / 64, 1), 512, 0, stream>>>(
            Achunk, B1t, K1, m, K1, b1, ln1_g, ln1_b, nullptr, h1ln, HID, n0);
    }
    // conv2 (+h1 residual)
    for (int n0 = 0; n0 < N_NODES; n0 += chunk) {
        int m = N_NODES - n0; if (m > chunk) m = chunk;
        agg2_kernel<<<(m + 3) / 4, 256, 0, stream>>>(h1ln, rp2, epk, Achunk, n0, m);
        gemm_fused<<<dim3((m + 63) / 64, 1), 512, 0, stream>>>(
            Achunk, B2t, K2, m, K2, b2, ln2_g, ln2_b, h1ln, hfin, HID, n0);
    }

    // U|V = hfin @ [W1_top | W1_bot]
    gemm_fused<<<dim3((N_NODES + 63) / 64, 2), 512, 0, stream>>>(
        hfin, wuvt, HID, N_NODES, HID, nullptr, nullptr, nullptr, nullptr, uvbuf, 512, 0);

    // edge decode
    edge_kernel<<<(M_DEC + 63) / 64, 256, 0, stream>>>(
        uvbuf, dec_edges, perm, mlp_b1, w2t, mlp_b2, mlp_w3, mlp_b3, (float*)d_out, M_DEC);
}